// Round 7
// baseline (5005.244 us; speedup 1.0000x reference)
//
#include <hip/hip_runtime.h>

// Problem constants: B=64, T=256, V=4096, H=512
// Inputs: x[B*T] i32, Wxh[V,H] f32, Whh[H,H] f32, bh[H] f32, Wo[H,V] f32, Bo[V] f32
// Output: out[B,T,V] f32 = (scan hs) @ Wo + Bo

typedef __fp16 half2_t __attribute__((ext_vector_type(2)));
typedef __attribute__((ext_vector_type(8))) short short8;   // 8 bf16 (MFMA A/B frag)
typedef __attribute__((ext_vector_type(4))) float f32x4;    // MFMA C/D frag

__device__ __forceinline__ unsigned short f32_to_bf16(float f) {
  unsigned int u = __builtin_bit_cast(unsigned int, f);
  u = (u + 0x7FFFu + ((u >> 16) & 1u)) >> 16;  // RNE
  return (unsigned short)u;
}

__device__ __forceinline__ unsigned int pack_f16x2(float a, float b) {
  half2_t h = __builtin_amdgcn_cvt_pkrtz(a, b);
  return __builtin_bit_cast(unsigned int, h);
}

__device__ __forceinline__ float fdot2_(unsigned int w, unsigned int h, float acc) {
  return __builtin_amdgcn_fdot2(__builtin_bit_cast(half2_t, w),
                                __builtin_bit_cast(half2_t, h), acc, false);
}

__device__ __forceinline__ void glds16(const void* g, void* lds) {
  __builtin_amdgcn_global_load_lds(
      (const __attribute__((address_space(1))) unsigned int*)g,
      (__attribute__((address_space(3))) unsigned int*)lds, 16, 0, 0);
}

// ---------------------------------------------------------------------------
// Prep 1: Whh -> WhhP4. Flat u32 idx = (((s*4+q)*16+u)*128 + c)*4 + cc holds
// f16 pair p = q*64 + u*4 + cc (h elems 2p,2p+1) of column j = s*128 + c.
// Matches scan thread (c,q) of slice-block s loading uint4 u at
// W4[((s*4+q)*16+u)*128 + c]  (consecutive c -> coalesced 16B).
// Block 0 also zeroes the sync flags (stream-ordered before rnn_scan4).
// ---------------------------------------------------------------------------
__global__ __launch_bounds__(256) void pack_whh4(const float* __restrict__ Whh,
                                                 unsigned int* __restrict__ WhhP4,
                                                 unsigned int* __restrict__ flags) {
  int idx = blockIdx.x * 256 + threadIdx.x;  // 131072 u32 total
  int cc = idx & 3;
  int c = (idx >> 2) & 127;
  int u = (idx >> 9) & 15;
  int q = (idx >> 13) & 3;
  int s = idx >> 15;
  int p = q * 64 + u * 4 + cc;   // f16-pair index 0..255
  int j = s * 128 + c;           // column
  float f0 = Whh[(2 * p) * 512 + j];
  float f1 = Whh[(2 * p + 1) * 512 + j];
  WhhP4[idx] = pack_f16x2(f0, f1);
  if (blockIdx.x == 0) {
    for (int k = threadIdx.x; k < 1024; k += 256) flags[k] = 0u;  // 64 batches x 16-pad
  }
}

// ---------------------------------------------------------------------------
// Prep 2: Wo [h][v] f32 -> WoT [v][h] bf16
// ---------------------------------------------------------------------------
__global__ __launch_bounds__(256) void transpose_wo(const float* __restrict__ Wo,
                                                    unsigned short* __restrict__ WoT) {
  __shared__ float tile[64][65];
  const int tv = blockIdx.x;   // 0..63  (V/64)
  const int th = blockIdx.y;   // 0..7   (H/64)
  const int tid = threadIdx.x;
  const int c = tid & 63, r4 = tid >> 6;
#pragma unroll
  for (int p = 0; p < 16; ++p) {
    int hl = p * 4 + r4;
    tile[hl][c] = Wo[(size_t)(th * 64 + hl) * 4096 + tv * 64 + c];
  }
  __syncthreads();
#pragma unroll
  for (int p = 0; p < 16; ++p) {
    int vl = p * 4 + r4;
    WoT[(size_t)(tv * 64 + vl) * 512 + th * 64 + c] = f32_to_bf16(tile[c][vl]);
  }
}

// ---------------------------------------------------------------------------
// Recurrence v4: Whh DISTRIBUTED. 256 blocks = 64 batches x 4 col-slices.
// Block (b,s) holds Whh[:, 128s..128s+127] f16 = 128 KB = 64 VGPR/thread at
// 512 threads (w0..w15 named uint4) -- inside the 128-VGPR ceiling the
// allocator enforced in R2-R6, so it finally stays resident. Per step the 4
// slice-blocks of batch b exchange h via global hG (double-buffered by step
// parity) with a per-batch monotonic flag counter: 2 release-posts per block
// per step (one per writer wave), readers spin to 8*t then agent-acquire
// fence. Co-residency guaranteed by capacity (2048 waves total). Thread
// (c=tid&127, q=tid>>7): 64 fdot2 on k-quarter q; partials reduced via LDS.
// ---------------------------------------------------------------------------
#define LW(u) const uint4 w##u = W4[wbase + (u) * 128];
#define DD(W, H) do { a0 = fdot2_(W.x, H.x, a0); a1 = fdot2_(W.y, H.y, a1); \
                      a2 = fdot2_(W.z, H.z, a2); a3 = fdot2_(W.w, H.w, a3); } while (0)

__global__ __launch_bounds__(512, 2) void rnn_scan4(const int* __restrict__ x,
                                                    const float* __restrict__ Wxh,
                                                    const unsigned int* __restrict__ WhhP4,
                                                    const float* __restrict__ bh,
                                                    unsigned short* __restrict__ hs,
                                                    unsigned short* hG16,
                                                    unsigned int* flags) {
  __shared__ float pbuf[512];
  __shared__ int toks[256];
  // XCD-swizzle (perf-only): co-locate the 4 slice-blocks of a batch on one
  // XCD under the bid%8 round-robin hypothesis.
  const int bid = blockIdx.x;
  const int xcd = bid & 7, m = bid >> 3;
  const int s = m & 3;                 // column-slice 0..3
  const int b = xcd + 8 * (m >> 2);    // batch 0..63
  const int tid = threadIdx.x;
  const int c = tid & 127, q = tid >> 7;
  const uint4* W4 = (const uint4*)WhhP4;
  const int wbase = ((s * 4 + q) * 16) * 128 + c;

  // 16 named uint4 = 64 VGPRs of weights: col j=128s+c, k in [128q,128q+128)
  LW(0)  LW(1)  LW(2)  LW(3)  LW(4)  LW(5)  LW(6)  LW(7)
  LW(8)  LW(9)  LW(10) LW(11) LW(12) LW(13) LW(14) LW(15)

  if (tid < 256) toks[tid] = x[b * 256 + tid];
  const float bhj = (tid < 128) ? bh[s * 128 + tid] : 0.f;
  __syncthreads();

  const uint4* hG4 = (const uint4*)hG16;       // [2][64][64] uint4
  unsigned int* flagb = flags + b * 16;        // 64B-padded per-batch counter

  for (int t = 0; t < 256; ++t) {
    const int tok = toks[t];
    if (t > 0) {
      if (tid == 0) {
        const unsigned tgt = 8u * (unsigned)t;
        while (__hip_atomic_load(flagb, __ATOMIC_RELAXED, __HIP_MEMORY_SCOPE_AGENT) < tgt)
          __builtin_amdgcn_s_sleep(1);
      }
      __syncthreads();
      __builtin_amdgcn_fence(__ATOMIC_ACQUIRE, "agent");  // per-wave: inv stale L1/L2
    }
    float xv = 0.f;
    if (tid < 128) xv = Wxh[(size_t)tok * 512 + s * 128 + tid];  // L2-hot, coalesced

    float a0 = 0.f, a1 = 0.f, a2 = 0.f, a3 = 0.f;
    if (t > 0) {
      const uint4* hb = hG4 + (((t - 1) & 1) << 12) + b * 64 + q * 16;
      // two 8-uint4 batches keep peak live regs ~120 (< the 128 ceiling)
      const uint4 hA0 = hb[0], hA1 = hb[1], hA2 = hb[2], hA3 = hb[3];
      const uint4 hA4 = hb[4], hA5 = hb[5], hA6 = hb[6], hA7 = hb[7];
      DD(w0, hA0); DD(w1, hA1); DD(w2, hA2); DD(w3, hA3);
      DD(w4, hA4); DD(w5, hA5); DD(w6, hA6); DD(w7, hA7);
      const uint4 hB0 = hb[8],  hB1 = hb[9],  hB2 = hb[10], hB3 = hb[11];
      const uint4 hB4 = hb[12], hB5 = hb[13], hB6 = hb[14], hB7 = hb[15];
      DD(w8, hB0);  DD(w9, hB1);  DD(w10, hB2); DD(w11, hB3);
      DD(w12, hB4); DD(w13, hB5); DD(w14, hB6); DD(w15, hB7);
    }
    pbuf[q * 128 + c] = (a0 + a1) + (a2 + a3);
    __syncthreads();

    if (tid < 128) {  // waves 0-1: finalize output j = 128s + tid
      const float ssum = pbuf[tid] + pbuf[tid + 128] + pbuf[tid + 256] + pbuf[tid + 384];
      const float u_ = xv + ssum + bhj;
      const float h = tanhf(u_);
      hs[(size_t)(b * 256 + t) * 512 + s * 128 + tid] = f32_to_bf16(h);
      half2_t hp2 = __builtin_amdgcn_cvt_pkrtz(h, h);
      unsigned int hu = __builtin_bit_cast(unsigned int, hp2);
      hG16[(size_t)((t & 1) * 64 + b) * 512 + s * 128 + tid] =
          (unsigned short)(hu & 0xFFFFu);
    }
    // each writer wave posts after ITS stores (release orders own-wave stores)
    if (tid < 128 && (tid & 63) == 0)
      __hip_atomic_fetch_add(flagb, 1u, __ATOMIC_RELEASE, __HIP_MEMORY_SCOPE_AGENT);
    __syncthreads();  // pbuf WAR before next iteration
  }
}

// ---------------------------------------------------------------------------
// Output GEMM: C[16384,4096] = A[16384,512](bf16) @ WoT^T + Bo.  m97 structure.
// ---------------------------------------------------------------------------
__global__ __launch_bounds__(256) void gemm_out(const unsigned short* __restrict__ A,
                                                const unsigned short* __restrict__ Bt,
                                                const float* __restrict__ Bo,
                                                float* __restrict__ C) {
  __shared__ alignas(16) unsigned short As[128 * 32];
  __shared__ alignas(16) unsigned short Bs[128 * 32];
  const int tid = threadIdx.x;
  const int lane = tid & 63, wid = tid >> 6;
  const int bn = blockIdx.x & 31, bm = blockIdx.x >> 5;
  const int wr = wid >> 1, wc = wid & 1;

  f32x4 acc[4][4] = {};

  const unsigned short* Ag = A + (size_t)(bm * 128 + (tid >> 2)) * 512 + (tid & 3) * 8;
  const unsigned short* Bg = Bt + (size_t)(bn * 128 + (tid >> 2)) * 512 + (tid & 3) * 8;
  char* AsW = (char*)As + wid * 1024;
  char* BsW = (char*)Bs + wid * 1024;

  const int laneRow = lane & 15;
  const int k0 = (lane >> 4) * 8;

  for (int kt = 0; kt < 16; ++kt) {
    __syncthreads();
    const unsigned short* a0 = Ag + kt * 32;
    const unsigned short* b0 = Bg + kt * 32;
    glds16(a0,            AsW);
    glds16(a0 + 64 * 512, AsW + 4096);
    glds16(b0,            BsW);
    glds16(b0 + 64 * 512, BsW + 4096);
    __syncthreads();

    short8 af[4], bf[4];
#pragma unroll
    for (int f = 0; f < 4; ++f)
      af[f] = *(const short8*)&As[(wr * 64 + f * 16 + laneRow) * 32 + k0];
#pragma unroll
    for (int f = 0; f < 4; ++f)
      bf[f] = *(const short8*)&Bs[(wc * 64 + f * 16 + laneRow) * 32 + k0];
#pragma unroll
    for (int fm = 0; fm < 4; ++fm)
#pragma unroll
      for (int fn = 0; fn < 4; ++fn)
        acc[fm][fn] = __builtin_amdgcn_mfma_f32_16x16x32_bf16(af[fm], bf[fn], acc[fm][fn], 0, 0, 0);
  }

  const int mg0 = bm * 128 + wr * 64, ng0 = bn * 128 + wc * 64;
#pragma unroll
  for (int fn = 0; fn < 4; ++fn) {
    const int col = ng0 + fn * 16 + laneRow;
    const float bo = Bo[col];
#pragma unroll
    for (int fm = 0; fm < 4; ++fm) {
      const int row0 = mg0 + fm * 16 + (lane >> 4) * 4;
#pragma unroll
      for (int r = 0; r < 4; ++r)
        C[(size_t)(row0 + r) * 4096 + col] = acc[fm][fn][r] + bo;
    }
  }
}

// ---------------------------------------------------------------------------
extern "C" void kernel_launch(void* const* d_in, const int* in_sizes, int n_in,
                              void* d_out, int out_size, void* d_ws, size_t ws_size,
                              hipStream_t stream) {
  (void)in_sizes; (void)n_in; (void)out_size; (void)ws_size;
  const int* x = (const int*)d_in[0];
  const float* Wxh = (const float*)d_in[1];
  const float* Whh = (const float*)d_in[2];
  const float* bh = (const float*)d_in[3];
  const float* Wo = (const float*)d_in[4];
  const float* Bo = (const float*)d_in[5];
  float* out = (float*)d_out;

  // workspace map (bytes):
  //   WhhP4  @ 0         512 KB
  //   WoT    @ 524288    4 MB
  //   hs     @ 4718592   16 MB
  //   hG16   @ 21495808  128 KB   (2 x 64 x 512 f16)
  //   flags  @ 21626880  4 KB     (64 batches x 16-pad u32)
  unsigned int* WhhP4 = (unsigned int*)d_ws;
  unsigned short* WoT = (unsigned short*)((char*)d_ws + 524288);
  unsigned short* hs = (unsigned short*)((char*)d_ws + 4718592);
  unsigned short* hG16 = (unsigned short*)((char*)d_ws + 21495808);
  unsigned int* flags = (unsigned int*)((char*)d_ws + 21626880);

  hipLaunchKernelGGL(pack_whh4, dim3(512), dim3(256), 0, stream, Whh, WhhP4, flags);
  hipLaunchKernelGGL(transpose_wo, dim3(64, 8), dim3(256), 0, stream, Wo, WoT);
  hipLaunchKernelGGL(rnn_scan4, dim3(256), dim3(512), 0, stream, x, Wxh, WhhP4, bh,
                     hs, hG16, flags);
  hipLaunchKernelGGL(gemm_out, dim3(4096), dim3(256), 0, stream, hs, WoT, Bo, out);
}

// Round 8
// 1050.624 us; speedup vs baseline: 4.7641x; 4.7641x over previous
//
#include <hip/hip_runtime.h>

// Problem constants: B=64, T=256, V=4096, H=512
// Inputs: x[B*T] i32, Wxh[V,H] f32, Whh[H,H] f32, bh[H] f32, Wo[H,V] f32, Bo[V] f32
// Output: out[B,T,V] f32 = (scan hs) @ Wo + Bo

typedef __fp16 half2_t __attribute__((ext_vector_type(2)));
typedef __attribute__((ext_vector_type(8))) short short8;   // 8 bf16 (MFMA A/B frag)
typedef __attribute__((ext_vector_type(4))) float f32x4;    // MFMA C/D frag

__device__ __forceinline__ unsigned short f32_to_bf16(float f) {
  unsigned int u = __builtin_bit_cast(unsigned int, f);
  u = (u + 0x7FFFu + ((u >> 16) & 1u)) >> 16;  // RNE
  return (unsigned short)u;
}

__device__ __forceinline__ unsigned int pack_f16x2(float a, float b) {
  half2_t h = __builtin_amdgcn_cvt_pkrtz(a, b);
  return __builtin_bit_cast(unsigned int, h);
}

__device__ __forceinline__ float fdot2_(unsigned int w, unsigned int h, float acc) {
  return __builtin_amdgcn_fdot2(__builtin_bit_cast(half2_t, w),
                                __builtin_bit_cast(half2_t, h), acc, false);
}

__device__ __forceinline__ void glds16(const void* g, void* lds) {
  __builtin_amdgcn_global_load_lds(
      (const __attribute__((address_space(1))) unsigned int*)g,
      (__attribute__((address_space(3))) unsigned int*)lds, 16, 0, 0);
}

// ---------------------------------------------------------------------------
// Prep 1: Whh -> WhhP5. uint4 index U = ((o*4+q)*16 + c)*64 + g (o=colgrp 0..7,
// q=k-quarter, c=chunk 0..15, g=lane 0..63) holds u32 k of f16 pair
// p = q*64 + c*4 + k (h elems 2p,2p+1) of column j = o*64 + g.
// Wave (fixed q) reading (o,c) at lanes g -> 1KB contiguous, coalesced.
// ---------------------------------------------------------------------------
__global__ __launch_bounds__(256) void pack_whh5(const float* __restrict__ Whh,
                                                 unsigned int* __restrict__ WhhP5) {
  int idx = blockIdx.x * 256 + threadIdx.x;  // 131072 u32 total
  int k = idx & 3;
  int U = idx >> 2;
  int g = U & 63;
  int c = (U >> 6) & 15;
  int q = (U >> 10) & 3;
  int o = U >> 12;
  int p = q * 64 + c * 4 + k;   // f16-pair index 0..255
  int j = o * 64 + g;           // column
  float f0 = Whh[(2 * p) * 512 + j];
  float f1 = Whh[(2 * p + 1) * 512 + j];
  WhhP5[idx] = pack_f16x2(f0, f1);
}

// ---------------------------------------------------------------------------
// Prep 2: Wo [h][v] f32 -> WoT [v][h] bf16
// ---------------------------------------------------------------------------
__global__ __launch_bounds__(256) void transpose_wo(const float* __restrict__ Wo,
                                                    unsigned short* __restrict__ WoT) {
  __shared__ float tile[64][65];
  const int tv = blockIdx.x;   // 0..63  (V/64)
  const int th = blockIdx.y;   // 0..7   (H/64)
  const int tid = threadIdx.x;
  const int c = tid & 63, r4 = tid >> 6;
#pragma unroll
  for (int p = 0; p < 16; ++p) {
    int hl = p * 4 + r4;
    tile[hl][c] = Wo[(size_t)(th * 64 + hl) * 4096 + tv * 64 + c];
  }
  __syncthreads();
#pragma unroll
  for (int p = 0; p < 16; ++p) {
    int vl = p * 4 + r4;
    WoT[(size_t)(tv * 64 + vl) * 512 + th * 64 + c] = f32_to_bf16(tile[c][vl]);
  }
}

// ---------------------------------------------------------------------------
// Recurrence v5: AGPR-pinned weights. 64 blocks x 256 threads (4 waves =
// 1/SIMD, 512-reg budget). Thread (g=tid&63, q=tid>>6) owns 8 cols j=o*64+g
// over k-quarter q: 512 u32 of f16-pair weights, split:
//   chunks 0-8  (288 u32) pinned in AGPRs via asm v_accvgpr_write (the asm is
//               opaque -> compiler CANNOT rematerialize, the R2-R7 failure)
//   chunks 9-12 (128 u32) in LDS (128 KB), full-BW per-lane reads
//   chunks 13-15 (96 u32) streamed from L2 each step (96 KB/block/step)
// h k-quarter read from LDS (wave-uniform addr -> broadcast). Partials
// reduced via LDS; 2 barriers/step.
// ---------------------------------------------------------------------------
#define AGD(o, c) unsigned int A##o##_##c##_0, A##o##_##c##_1, A##o##_##c##_2, A##o##_##c##_3;
#define AGDO(o) AGD(o,0) AGD(o,1) AGD(o,2) AGD(o,3) AGD(o,4) AGD(o,5) AGD(o,6) AGD(o,7) AGD(o,8)

#define PIN4(o, c) { uint4 v_ = W4[(((o) * 4 + q) * 16 + (c)) * 64 + g]; \
  asm volatile("v_accvgpr_write_b32 %0, %1" : "=a"(A##o##_##c##_0) : "v"(v_.x)); \
  asm volatile("v_accvgpr_write_b32 %0, %1" : "=a"(A##o##_##c##_1) : "v"(v_.y)); \
  asm volatile("v_accvgpr_write_b32 %0, %1" : "=a"(A##o##_##c##_2) : "v"(v_.z)); \
  asm volatile("v_accvgpr_write_b32 %0, %1" : "=a"(A##o##_##c##_3) : "v"(v_.w)); }
#define PINO(o) PIN4(o,0) PIN4(o,1) PIN4(o,2) PIN4(o,3) PIN4(o,4) PIN4(o,5) PIN4(o,6) PIN4(o,7) PIN4(o,8)

#define ADOT4(o, c, HC) { unsigned int t0_, t1_, t2_, t3_; \
  asm volatile("v_accvgpr_read_b32 %0, %1" : "=v"(t0_) : "a"(A##o##_##c##_0)); \
  asm volatile("v_accvgpr_read_b32 %0, %1" : "=v"(t1_) : "a"(A##o##_##c##_1)); \
  asm volatile("v_accvgpr_read_b32 %0, %1" : "=v"(t2_) : "a"(A##o##_##c##_2)); \
  asm volatile("v_accvgpr_read_b32 %0, %1" : "=v"(t3_) : "a"(A##o##_##c##_3)); \
  acc##o = fdot2_(t0_, HC.x, acc##o); acc##o = fdot2_(t1_, HC.y, acc##o); \
  acc##o = fdot2_(t2_, HC.z, acc##o); acc##o = fdot2_(t3_, HC.w, acc##o); }

#define ACHUNK(c) { const uint4 hc_ = hb[q16 + (c)]; \
  ADOT4(0,c,hc_) ADOT4(1,c,hc_) ADOT4(2,c,hc_) ADOT4(3,c,hc_) \
  ADOT4(4,c,hc_) ADOT4(5,c,hc_) ADOT4(6,c,hc_) ADOT4(7,c,hc_) }

#define LDOT(o, cc, HC) { const uint4 w_ = wlds[(((o) * 4 + q) * 4 + (cc)) * 64 + g]; \
  acc##o = fdot2_(w_.x, HC.x, acc##o); acc##o = fdot2_(w_.y, HC.y, acc##o); \
  acc##o = fdot2_(w_.z, HC.z, acc##o); acc##o = fdot2_(w_.w, HC.w, acc##o); }

#define LCHUNK(cc) { const uint4 hc_ = hb[q16 + 9 + (cc)]; \
  LDOT(0,cc,hc_) LDOT(1,cc,hc_) LDOT(2,cc,hc_) LDOT(3,cc,hc_) \
  LDOT(4,cc,hc_) LDOT(5,cc,hc_) LDOT(6,cc,hc_) LDOT(7,cc,hc_) }

#define SDEF(c) uint4 S##c##_0, S##c##_1, S##c##_2, S##c##_3, S##c##_4, S##c##_5, S##c##_6, S##c##_7;
#define SLOAD(c) { \
  S##c##_0 = W4[((0*4+q)*16 + (c))*64 + g]; S##c##_1 = W4[((1*4+q)*16 + (c))*64 + g]; \
  S##c##_2 = W4[((2*4+q)*16 + (c))*64 + g]; S##c##_3 = W4[((3*4+q)*16 + (c))*64 + g]; \
  S##c##_4 = W4[((4*4+q)*16 + (c))*64 + g]; S##c##_5 = W4[((5*4+q)*16 + (c))*64 + g]; \
  S##c##_6 = W4[((6*4+q)*16 + (c))*64 + g]; S##c##_7 = W4[((7*4+q)*16 + (c))*64 + g]; }
#define SDOT1(o, c, HC) { \
  acc##o = fdot2_(S##c##_##o.x, HC.x, acc##o); acc##o = fdot2_(S##c##_##o.y, HC.y, acc##o); \
  acc##o = fdot2_(S##c##_##o.z, HC.z, acc##o); acc##o = fdot2_(S##c##_##o.w, HC.w, acc##o); }
#define SCHUNK(c) { const uint4 hc_ = hb[q16 + (c)]; \
  SDOT1(0,c,hc_) SDOT1(1,c,hc_) SDOT1(2,c,hc_) SDOT1(3,c,hc_) \
  SDOT1(4,c,hc_) SDOT1(5,c,hc_) SDOT1(6,c,hc_) SDOT1(7,c,hc_) }

__global__ __launch_bounds__(256)
__attribute__((amdgpu_waves_per_eu(1, 1)))
void rnn_scan5(const int* __restrict__ x,
               const float* Wxh,
               const unsigned int* WhhP5,
               const float* __restrict__ bh,
               unsigned short* hs) {
  __shared__ uint4 wlds[8192];     // 128 KB: weight chunks 9-12
  __shared__ uint4 hbuf[128];      // 2 x 512 h f16 (double buffer)
  __shared__ float pbuf[2048];     // partials [q][j]
  __shared__ int toks[256];
  const int b = blockIdx.x;
  const int tid = threadIdx.x;
  const int g = tid & 63;
  const int q = tid >> 6;          // wave id = k-quarter
  const int q16 = q * 16;
  const uint4* W4 = (const uint4*)WhhP5;

  // --- AGPR pin: chunks 0-8, 8 cols -> 288 AGPRs ---
  AGDO(0) AGDO(1) AGDO(2) AGDO(3) AGDO(4) AGDO(5) AGDO(6) AGDO(7)
  PINO(0) PINO(1) PINO(2) PINO(3) PINO(4) PINO(5) PINO(6) PINO(7)

  // --- LDS weights: chunks 9-12 (layout ((o*4+q)*4+cc)*64+g) ---
#pragma unroll
  for (int it = 0; it < 32; ++it) {
    int L = it * 256 + tid;
    int gg = L & 63, cc = (L >> 6) & 3, qq = (L >> 8) & 3, oo = L >> 10;
    wlds[L] = W4[((oo * 4 + qq) * 16 + 9 + cc) * 64 + gg];
  }
  if (tid < 64) hbuf[tid] = make_uint4(0u, 0u, 0u, 0u);  // h0 = 0 (buf 0)
  toks[tid] = x[b * 256 + tid];
  const float bh1 = bh[tid], bh2 = bh[tid + 256];
  __syncthreads();

  unsigned short* hb16 = (unsigned short*)hbuf;  // [2][512] u16 view

  for (int t = 0; t < 256; ++t) {
    asm volatile("" ::: "memory");  // block cross-iteration hoist of stream loads
    const int cur = t & 1;
    const uint4* hb = hbuf + cur * 64;
    const int tok = toks[t];

    SDEF(13) SDEF(14) SDEF(15)
    SLOAD(13) SLOAD(14) SLOAD(15)   // 24 L2 loads in flight; consumed last

    const float xv1 = Wxh[(size_t)tok * 512 + tid];
    const float xv2 = Wxh[(size_t)tok * 512 + 256 + tid];

    float acc0 = 0.f, acc1 = 0.f, acc2 = 0.f, acc3 = 0.f;
    float acc4 = 0.f, acc5 = 0.f, acc6 = 0.f, acc7 = 0.f;

    ACHUNK(0) ACHUNK(1) ACHUNK(2) ACHUNK(3) ACHUNK(4)
    ACHUNK(5) ACHUNK(6) ACHUNK(7) ACHUNK(8)
    LCHUNK(0) LCHUNK(1) LCHUNK(2) LCHUNK(3)
    SCHUNK(13) SCHUNK(14) SCHUNK(15)

    pbuf[q * 512 + 0 * 64 + g] = acc0;
    pbuf[q * 512 + 1 * 64 + g] = acc1;
    pbuf[q * 512 + 2 * 64 + g] = acc2;
    pbuf[q * 512 + 3 * 64 + g] = acc3;
    pbuf[q * 512 + 4 * 64 + g] = acc4;
    pbuf[q * 512 + 5 * 64 + g] = acc5;
    pbuf[q * 512 + 6 * 64 + g] = acc6;
    pbuf[q * 512 + 7 * 64 + g] = acc7;
    __syncthreads();

    // finalize outputs j = tid and j = tid + 256
    const float s1 = pbuf[tid] + pbuf[512 + tid] + pbuf[1024 + tid] + pbuf[1536 + tid];
    const float s2 = pbuf[tid + 256] + pbuf[512 + tid + 256] +
                     pbuf[1024 + tid + 256] + pbuf[1536 + tid + 256];
    const float h1 = tanhf(xv1 + s1 + bh1);
    const float h2 = tanhf(xv2 + s2 + bh2);
    const size_t orow = (size_t)(b * 256 + t) * 512;
    hs[orow + tid] = f32_to_bf16(h1);
    hs[orow + 256 + tid] = f32_to_bf16(h2);
    const int nxt = cur ^ 1;
    {
      half2_t p1 = __builtin_amdgcn_cvt_pkrtz(h1, h1);
      half2_t p2 = __builtin_amdgcn_cvt_pkrtz(h2, h2);
      hb16[nxt * 512 + tid] = (unsigned short)(__builtin_bit_cast(unsigned int, p1) & 0xFFFFu);
      hb16[nxt * 512 + 256 + tid] = (unsigned short)(__builtin_bit_cast(unsigned int, p2) & 0xFFFFu);
    }
    __syncthreads();  // next h buffer complete; pbuf reusable
  }
}

// ---------------------------------------------------------------------------
// Output GEMM: C[16384,4096] = A[16384,512](bf16) @ WoT^T + Bo.  m97 structure.
// ---------------------------------------------------------------------------
__global__ __launch_bounds__(256) void gemm_out(const unsigned short* __restrict__ A,
                                                const unsigned short* __restrict__ Bt,
                                                const float* __restrict__ Bo,
                                                float* __restrict__ C) {
  __shared__ alignas(16) unsigned short As[128 * 32];
  __shared__ alignas(16) unsigned short Bs[128 * 32];
  const int tid = threadIdx.x;
  const int lane = tid & 63, wid = tid >> 6;
  const int bn = blockIdx.x & 31, bm = blockIdx.x >> 5;
  const int wr = wid >> 1, wc = wid & 1;

  f32x4 acc[4][4] = {};

  const unsigned short* Ag = A + (size_t)(bm * 128 + (tid >> 2)) * 512 + (tid & 3) * 8;
  const unsigned short* Bg = Bt + (size_t)(bn * 128 + (tid >> 2)) * 512 + (tid & 3) * 8;
  char* AsW = (char*)As + wid * 1024;
  char* BsW = (char*)Bs + wid * 1024;

  const int laneRow = lane & 15;
  const int k0 = (lane >> 4) * 8;

  for (int kt = 0; kt < 16; ++kt) {
    __syncthreads();
    const unsigned short* a0 = Ag + kt * 32;
    const unsigned short* b0 = Bg + kt * 32;
    glds16(a0,            AsW);
    glds16(a0 + 64 * 512, AsW + 4096);
    glds16(b0,            BsW);
    glds16(b0 + 64 * 512, BsW + 4096);
    __syncthreads();

    short8 af[4], bf[4];
#pragma unroll
    for (int f = 0; f < 4; ++f)
      af[f] = *(const short8*)&As[(wr * 64 + f * 16 + laneRow) * 32 + k0];
#pragma unroll
    for (int f = 0; f < 4; ++f)
      bf[f] = *(const short8*)&Bs[(wc * 64 + f * 16 + laneRow) * 32 + k0];
#pragma unroll
    for (int fm = 0; fm < 4; ++fm)
#pragma unroll
      for (int fn = 0; fn < 4; ++fn)
        acc[fm][fn] = __builtin_amdgcn_mfma_f32_16x16x32_bf16(af[fm], bf[fn], acc[fm][fn], 0, 0, 0);
  }

  const int mg0 = bm * 128 + wr * 64, ng0 = bn * 128 + wc * 64;
#pragma unroll
  for (int fn = 0; fn < 4; ++fn) {
    const int col = ng0 + fn * 16 + laneRow;
    const float bo = Bo[col];
#pragma unroll
    for (int fm = 0; fm < 4; ++fm) {
      const int row0 = mg0 + fm * 16 + (lane >> 4) * 4;
#pragma unroll
      for (int r = 0; r < 4; ++r)
        C[(size_t)(row0 + r) * 4096 + col] = acc[fm][fn][r] + bo;
    }
  }
}

// ---------------------------------------------------------------------------
extern "C" void kernel_launch(void* const* d_in, const int* in_sizes, int n_in,
                              void* d_out, int out_size, void* d_ws, size_t ws_size,
                              hipStream_t stream) {
  (void)in_sizes; (void)n_in; (void)out_size; (void)ws_size;
  const int* x = (const int*)d_in[0];
  const float* Wxh = (const float*)d_in[1];
  const float* Whh = (const float*)d_in[2];
  const float* bh = (const float*)d_in[3];
  const float* Wo = (const float*)d_in[4];
  const float* Bo = (const float*)d_in[5];
  float* out = (float*)d_out;

  // workspace: WhhP5 512KB | WoT 4MB | hs 16MB
  unsigned int* WhhP5 = (unsigned int*)d_ws;
  unsigned short* WoT = (unsigned short*)((char*)d_ws + 524288);
  unsigned short* hs = (unsigned short*)((char*)d_ws + 4718592);

  hipLaunchKernelGGL(pack_whh5, dim3(512), dim3(256), 0, stream, Whh, WhhP5);
  hipLaunchKernelGGL(transpose_wo, dim3(64, 8), dim3(256), 0, stream, Wo, WoT);
  hipLaunchKernelGGL(rnn_scan5, dim3(64), dim3(256), 0, stream, x, Wxh, WhhP5, bh, hs);
  hipLaunchKernelGGL(gemm_out, dim3(4096), dim3(256), 0, stream, hs, WoT, Bo, out);
}